// Round 15
// baseline (188.946 us; speedup 1.0000x reference)
//
#include <hip/hip_runtime.h>
#include <math.h>

// Problem constants
constexpr int kB   = 4;
constexpr int kL   = 1024;
constexpr int kDM  = 768;
constexpr int kDI  = 1536;   // 2*kDM
constexpr int kDS  = 16;     // D_STATE
constexpr int kDTR = 48;     // DT_RANK
constexpr int kNX  = 80;     // DTR + 2*DS
constexpr int kM   = kB * kL; // 4096
constexpr int kLTXT = 128;

typedef __attribute__((ext_vector_type(8))) short bf16x8;
typedef __attribute__((ext_vector_type(4))) float f32x4;
typedef __attribute__((ext_vector_type(8))) unsigned short u16x8;

__device__ inline unsigned short f2bf(float f) {
    unsigned u = __float_as_uint(f);
    u = (u + 0x7FFFu + ((u >> 16) & 1u)) >> 16;   // RNE
    return (unsigned short)u;
}
__device__ inline float bf2f(unsigned short us) {
    return __uint_as_float((unsigned)us << 16);
}

__device__ __forceinline__ void gl2lds16(const unsigned short* g, unsigned short* l) {
    __builtin_amdgcn_global_load_lds(
        (const __attribute__((address_space(1))) unsigned int*)g,
        (__attribute__((address_space(3))) unsigned int*)l, 16, 0, 0);
}

// ---------------------------------------------------------------------------
// txt[b][j] = b_txt[j] + sum_k text_tokens[b,0,k] * W_txt[j,k]
__global__ __launch_bounds__(256) void txt_kernel(
    const float* __restrict__ text, const float* __restrict__ Wt,
    const float* __restrict__ bt, float* __restrict__ txt)
{
    int gw = blockIdx.x * 4 + (threadIdx.x >> 6);
    int lane = threadIdx.x & 63;
    int b = gw / kDM;
    int j = gw - b * kDM;
    const float* trow = text + (size_t)b * kLTXT * kDM;
    const float* wrow = Wt + (size_t)j * kDM;
    float acc = 0.f;
    for (int k = lane; k < kDM; k += 64) acc = fmaf(trow[k], wrow[k], acc);
    #pragma unroll
    for (int o = 32; o; o >>= 1) acc += __shfl_xor(acc, o, 64);
    if (lane == 0) txt[gw] = acc + bt[j];
}

// ---------------------------------------------------------------------------
// Merged prep: blocks [0,3072): tokens_bf16 = bf16(image + txt)
//              blocks [3072,5376): cast in_proj_w -> bf16
__global__ __launch_bounds__(256) void prep_kernel(
    const float* __restrict__ img, const float* __restrict__ txt,
    unsigned short* __restrict__ tok,
    const float* __restrict__ w, unsigned short* __restrict__ wb)
{
    const int bid = blockIdx.x;
    if (bid < 3072) {
        int i = bid * 256 + threadIdx.x;           // over kM*kDM/4
        float4 a = ((const float4*)img)[i];
        int m = i / (kDM / 4);
        int k4 = i - m * (kDM / 4);
        float4 tv = ((const float4*)(txt + (size_t)(m >> 10) * kDM))[k4];
        ushort4 o;
        o.x = f2bf(a.x + tv.x); o.y = f2bf(a.y + tv.y);
        o.z = f2bf(a.z + tv.z); o.w = f2bf(a.w + tv.w);
        ((ushort4*)tok)[i] = o;
    } else {
        int i = (bid - 3072) * 256 + threadIdx.x;  // over 2*kDI*kDM/4
        float4 a = ((const float4*)w)[i];
        ushort4 v;
        v.x = f2bf(a.x); v.y = f2bf(a.y); v.z = f2bf(a.z); v.w = f2bf(a.w);
        ((ushort4*)wb)[i] = v;
    }
}

// ---------------------------------------------------------------------------
// bf16 MFMA GEMM for in_proj (global_load_lds width-16, double-buffered LDS).
// M=4096, N=3072, K=768. BM=BN=128, BK=32, 256 threads (4 waves, 2x2).
// n<1536 -> xout = bf16(v); n>=1536 -> gout = bf16(silu(v))
__global__ __launch_bounds__(256) void mfma_inproj_kernel(
    const unsigned short* __restrict__ A, const unsigned short* __restrict__ W,
    unsigned short* __restrict__ xout, unsigned short* __restrict__ gout)
{
    __shared__ unsigned short Asm[2][128][32];
    __shared__ unsigned short Wsm[2][128][32];
    const int t = threadIdx.x;
    const int lane = t & 63;
    const int wv = t >> 6;             // wave 0..3
    const int wr = wv >> 1, wc = wv & 1;
    const int m0 = blockIdx.x * 128;
    const int n0 = blockIdx.y * 128;

    const int srow = lane >> 2;          // 0..15
    const int scol = (lane & 3) * 8;     // bf16 elem 0,8,16,24
    const unsigned short* agp  = A + (size_t)(m0 + wv * 32 + srow) * kDM + scol;
    const unsigned short* agp2 = agp + 16 * kDM;
    const unsigned short* wgp  = W + (size_t)(n0 + wv * 32 + srow) * kDM + scol;
    const unsigned short* wgp2 = wgp + 16 * kDM;

    auto stage = [&](int buf, int k0) {
        gl2lds16(agp  + k0, &Asm[buf][wv * 32][0]);
        gl2lds16(agp2 + k0, &Asm[buf][wv * 32 + 16][0]);
        gl2lds16(wgp  + k0, &Wsm[buf][wv * 32][0]);
        gl2lds16(wgp2 + k0, &Wsm[buf][wv * 32 + 16][0]);
    };

    f32x4 acc[4][4] = {};
    const int fr = lane & 15;
    const int fk = (lane >> 4) * 8;

    stage(0, 0);
    __syncthreads();

    int buf = 0;
    for (int k0 = 0; k0 < kDM; k0 += 32) {
        if (k0 + 32 < kDM) stage(buf ^ 1, k0 + 32);
        bf16x8 af[4], wf[4];
        #pragma unroll
        for (int i = 0; i < 4; ++i)
            af[i] = *(const bf16x8*)&Asm[buf][wr * 64 + i * 16 + fr][fk];
        #pragma unroll
        for (int j = 0; j < 4; ++j)
            wf[j] = *(const bf16x8*)&Wsm[buf][wc * 64 + j * 16 + fr][fk];
        #pragma unroll
        for (int i = 0; i < 4; ++i)
            #pragma unroll
            for (int j = 0; j < 4; ++j)
                acc[i][j] = __builtin_amdgcn_mfma_f32_16x16x32_bf16(af[i], wf[j], acc[i][j], 0, 0, 0);
        __syncthreads();
        buf ^= 1;
    }

    const int erow = (lane >> 4) * 4;
    const int ecol = lane & 15;
    #pragma unroll
    for (int i = 0; i < 4; ++i) {
        #pragma unroll
        for (int j = 0; j < 4; ++j) {
            const int gn = n0 + wc * 64 + j * 16 + ecol;
            #pragma unroll
            for (int q = 0; q < 4; ++q) {
                const int gm = m0 + wr * 64 + i * 16 + erow + q;
                float v = acc[i][j][q];
                if (gn < kDI) {
                    xout[(size_t)gm * kDI + gn] = f2bf(v);
                } else {
                    gout[(size_t)gm * kDI + (gn - kDI)] = f2bf(v / (1.f + __expf(-v)));
                }
            }
        }
    }
}

// ---------------------------------------------------------------------------
// causal depthwise conv (k=4) + SiLU: bf16 in, bf16 out, f32 math.
// 8 channels per thread (16B loads/stores).
__global__ __launch_bounds__(256) void conv_silu_kernel(
    const unsigned short* __restrict__ xraw, const float* __restrict__ cw,
    const float* __restrict__ cb, unsigned short* __restrict__ xout)
{
    int i = blockIdx.x * 256 + threadIdx.x;     // over kM*kDI/8
    int d8 = i % (kDI / 8);
    int ml = i / (kDI / 8);
    int l = ml & (kL - 1);
    const int d = d8 * 8;
    float acc[8];
    *(float4*)&acc[0] = *(const float4*)&cb[d];
    *(float4*)&acc[4] = *(const float4*)&cb[d + 4];
    const unsigned short* base = xraw + (size_t)ml * kDI + d - 3 * (size_t)kDI;
    float4 cwv[8];
    #pragma unroll
    for (int e = 0; e < 8; ++e) cwv[e] = *(const float4*)&cw[(d + e) * 4];
    #pragma unroll
    for (int j = 0; j < 4; ++j) {
        if (l - 3 + j >= 0) {
            u16x8 xv = *(const u16x8*)(base + (size_t)j * kDI);
            #pragma unroll
            for (int e = 0; e < 8; ++e)
                acc[e] = fmaf(bf2f(xv[e]), ((const float*)&cwv[e])[j], acc[e]);
        }
    }
    u16x8 o;
    #pragma unroll
    for (int e = 0; e < 8; ++e)
        o[e] = f2bf(acc[e] / (1.f + __expf(-acc[e])));
    *(u16x8*)(xout + (size_t)ml * kDI + d) = o;
}

// ---------------------------------------------------------------------------
// x_proj split-K (bf16 A): part[ks][m][n] = sum_{k in seg ks} x[m][k]*W[n][k]
constexpr int kKS   = 8;
constexpr int kKSEG = kDI / kKS;   // 192

__global__ __launch_bounds__(256) void xproj_splitk_kernel(
    const unsigned short* __restrict__ A, const float* __restrict__ W,
    float* __restrict__ part)
{
    __shared__ float As[16][68];
    __shared__ float Ws[16][84];
    const int t = threadIdx.x;
    const int m0 = blockIdx.x * 64;
    const int kbase = blockIdx.y * kKSEG;
    const int lrow = t >> 2, lk4 = (t & 3) << 2;
    const int ci = (t & 15) << 2;      // 4 rows
    const int cj = (t >> 4) * 5;       // 5 cols (16*5 = 80)
    float acc[4][5] = {};
    const unsigned short* aptr = A + (size_t)(m0 + lrow) * kDI + kbase + lk4;

    for (int k0 = 0; k0 < kKSEG; k0 += 16) {
        ushort4 av = *(const ushort4*)(aptr + k0);
        if (k0) __syncthreads();
        As[lk4+0][lrow] = bf2f(av.x); As[lk4+1][lrow] = bf2f(av.y);
        As[lk4+2][lrow] = bf2f(av.z); As[lk4+3][lrow] = bf2f(av.w);
        #pragma unroll
        for (int i = 0; i < 5; ++i) {
            int idx = t + 256 * i;
            int n = idx % 80;
            int k = idx / 80;
            Ws[k][n] = W[(size_t)n * kDI + kbase + k0 + k];
        }
        __syncthreads();
        #pragma unroll
        for (int k = 0; k < 16; ++k) {
            const float4 a4 = *(const float4*)&As[k][ci];
            const float aa[4] = {a4.x, a4.y, a4.z, a4.w};
            float ww[5];
            #pragma unroll
            for (int j = 0; j < 5; ++j) ww[j] = Ws[k][cj + j];
            #pragma unroll
            for (int i = 0; i < 4; ++i)
                #pragma unroll
                for (int j = 0; j < 5; ++j)
                    acc[i][j] = fmaf(aa[i], ww[j], acc[i][j]);
        }
    }

    float* pbase = part + ((size_t)blockIdx.y * kM) * kNX;
    #pragma unroll
    for (int i = 0; i < 4; ++i)
        #pragma unroll
        for (int j = 0; j < 5; ++j)
            pbase[(size_t)(m0 + ci + i) * kNX + cj + j] = acc[i][j];
}

__global__ __launch_bounds__(256) void xproj_reduce_kernel(
    const float* __restrict__ part, float* __restrict__ xdbl)
{
    int i = blockIdx.x * 256 + threadIdx.x;    // over kM*kNX
    float s = 0.f;
    #pragma unroll
    for (int k = 0; k < kKS; ++k) s += part[(size_t)k * kM * kNX + i];
    xdbl[i] = s;
}

// ---------------------------------------------------------------------------
// dt_proj (proven round-2 gemm structure, VGPR ~36) -> bf16 output.
// dt[m][n] = softplus(sum_k xdbl[m][k]*Wd[n][k] + b[n]); K=48, BK=16.
__global__ __launch_bounds__(256) void dtproj_gemm_kernel(
    const float* __restrict__ A, const float* __restrict__ W,
    const float* __restrict__ bias, unsigned short* __restrict__ dt)
{
    __shared__ float As[16][68];
    __shared__ float Ws[16][68];
    const int t = threadIdx.x;
    const int m0 = blockIdx.x * 64;
    const int n0 = blockIdx.y * 64;
    const int lrow = t >> 2;          // 0..63
    const int lk4  = (t & 3) << 2;    // 0,4,8,12
    const int ci   = (t & 15) << 2;
    const int cj   = (t >> 4) << 2;
    float acc[4][4] = {};
    const float* aptr = A + (size_t)(m0 + lrow) * kNX + lk4;
    const float* wptr = W + (size_t)(n0 + lrow) * kDTR + lk4;

    for (int k0 = 0; k0 < kDTR; k0 += 16) {
        float4 av = *(const float4*)(aptr + k0);
        float4 wv = *(const float4*)(wptr + k0);
        if (k0) __syncthreads();
        As[lk4+0][lrow] = av.x; As[lk4+1][lrow] = av.y;
        As[lk4+2][lrow] = av.z; As[lk4+3][lrow] = av.w;
        Ws[lk4+0][lrow] = wv.x; Ws[lk4+1][lrow] = wv.y;
        Ws[lk4+2][lrow] = wv.z; Ws[lk4+3][lrow] = wv.w;
        __syncthreads();
        #pragma unroll
        for (int k = 0; k < 16; ++k) {
            const float4 a4 = *(const float4*)&As[k][ci];
            const float4 w4 = *(const float4*)&Ws[k][cj];
            const float aa[4] = {a4.x, a4.y, a4.z, a4.w};
            const float ww[4] = {w4.x, w4.y, w4.z, w4.w};
            #pragma unroll
            for (int i = 0; i < 4; ++i)
                #pragma unroll
                for (int j = 0; j < 4; ++j)
                    acc[i][j] = fmaf(aa[i], ww[j], acc[i][j]);
        }
    }

    #pragma unroll
    for (int i = 0; i < 4; ++i) {
        const int gm = m0 + ci + i;
        ushort4 o;
        unsigned short* op = (unsigned short*)&o;
        #pragma unroll
        for (int j = 0; j < 4; ++j) {
            float v = acc[i][j] + bias[n0 + cj + j];
            v = (v > 20.f) ? v : log1pf(__expf(v));   // softplus
            op[j] = f2bf(v);
        }
        *(ushort4*)&dt[(size_t)gm * kDI + n0 + cj] = o;
    }
}

// ---------------------------------------------------------------------------
// Selective scan v12: bf16 u/g/dt inputs (f32 conversion at staging time).
// Block = 64 channels x 4 state-quads; 16 segments x 64 steps; kCT=16
// single-round full residency. LDS 14.1 KB.
constexpr int kNSEG = 16;
constexpr int kSEGL = kL / kNSEG;     // 64
constexpr int kCT   = 16;             // steps per chunk
constexpr int kBD   = kB * kDI;       // 6144
constexpr int kP    = kBD * 16;       // 98304 (b,d,s) tuples
constexpr float kLOG2E = 1.44269504089f;

__global__ __launch_bounds__(256, 6) void scan12_kernel(
    const unsigned short* __restrict__ u, const unsigned short* __restrict__ g,
    const unsigned short* __restrict__ dt, const float* __restrict__ xdbl,
    const float* __restrict__ A_log,
    float* __restrict__ PA, float* __restrict__ QA,
    float* __restrict__ accA, float* __restrict__ wcA,
    float* __restrict__ ugA)
{
    __shared__ float uS [kCT][64];     // 4 KB
    __shared__ float gS [kCT][64];     // 4 KB
    __shared__ float dtS[kCT][64];     // 4 KB
    __shared__ float bcS[kCT][34];     // B|C (32 used) + pad   2.1 KB
    const int t = threadIdx.x;
    const int blk = blockIdx.x;          // grid = 96 * kNSEG = 1536
    const int seg = blk & (kNSEG - 1);
    const int bd  = blk >> 4;            // 0..95
    const int b   = bd / 24;
    const int d0  = (bd % 24) * 64;
    const int c   = t & 63;              // channel
    const int sq  = t >> 6;              // state-quad (wave-uniform)
    const int d   = d0 + c;
    const int lb  = seg * kSEGL;

    f32x4 Av;
    {
        float4 al = *(const float4*)&A_log[d * kDS + sq * 4];
        Av.x = -__expf(al.x) * kLOG2E;
        Av.y = -__expf(al.y) * kLOG2E;
        Av.z = -__expf(al.z) * kLOG2E;
        Av.w = -__expf(al.w) * kLOG2E;
    }

    const unsigned short* u_base  = u  + ((size_t)b << 10) * kDI + d0;
    const unsigned short* g_base  = g  + ((size_t)b << 10) * kDI + d0;
    const unsigned short* dt_base = dt + ((size_t)b << 10) * kDI + d0;
    const float* bc_base = xdbl + ((size_t)b << 10) * kNX + kDTR;
    const int th = t & 127;
    const int hr = th >> 3, hc = (th & 7) * 8;    // u/g/dt: [16][64] u16x8
    const int rb = th >> 3, cbo = (th & 7) * 4;   // bc: [16][32] float4

    u16x8 r0, r1;
    float4 rbc;
    auto load_chunk = [&](int l0) {
        if (t < 128) {
            r0  = *(const u16x8*)(u_base + (size_t)(l0 + hr) * kDI + hc);
            rbc = *(const float4*)(bc_base + (size_t)(l0 + rb) * kNX + cbo);
        } else {
            r0 = *(const u16x8*)(g_base  + (size_t)(l0 + hr) * kDI + hc);
            r1 = *(const u16x8*)(dt_base + (size_t)(l0 + hr) * kDI + hc);
        }
    };
    auto store_chunk = [&]() {
        float4 lo, hi;
        lo.x = bf2f(r0[0]); lo.y = bf2f(r0[1]);
        lo.z = bf2f(r0[2]); lo.w = bf2f(r0[3]);
        hi.x = bf2f(r0[4]); hi.y = bf2f(r0[5]);
        hi.z = bf2f(r0[6]); hi.w = bf2f(r0[7]);
        if (t < 128) {
            *(float4*)&uS[hr][hc]     = lo;
            *(float4*)&uS[hr][hc + 4] = hi;
            *(float4*)&bcS[rb][cbo]   = rbc;
        } else {
            *(float4*)&gS[hr][hc]     = lo;
            *(float4*)&gS[hr][hc + 4] = hi;
            float4 l2, h2;
            l2.x = bf2f(r1[0]); l2.y = bf2f(r1[1]);
            l2.z = bf2f(r1[2]); l2.w = bf2f(r1[3]);
            h2.x = bf2f(r1[4]); h2.y = bf2f(r1[5]);
            h2.z = bf2f(r1[6]); h2.w = bf2f(r1[7]);
            *(float4*)&dtS[hr][hc]     = l2;
            *(float4*)&dtS[hr][hc + 4] = h2;
        }
    };

    f32x4 h   = {0.f, 0.f, 0.f, 0.f};
    f32x4 cp  = {1.f, 1.f, 1.f, 1.f};
    f32x4 acc = {0.f, 0.f, 0.f, 0.f};
    f32x4 wc  = {0.f, 0.f, 0.f, 0.f};
    float ug = 0.f;

    load_chunk(lb);
    store_chunk();
    __syncthreads();

    #pragma unroll
    for (int ck = 0; ck < kSEGL / kCT; ++ck) {
        if (ck + 1 < kSEGL / kCT) load_chunk(lb + (ck + 1) * kCT);
        #pragma unroll 8
        for (int i = 0; i < kCT; ++i) {
            const float dtv = dtS[i][c];
            const float uv  = uS [i][c];
            const float gv  = gS [i][c];
            const f32x4 Bv = *(const f32x4*)&bcS[i][sq * 4];        // uniform
            const f32x4 Cv = *(const f32x4*)&bcS[i][16 + sq * 4];   // uniform
            const f32x4 pm = dtv * Av;
            f32x4 dA;
            dA.x = exp2f(pm.x); dA.y = exp2f(pm.y);
            dA.z = exp2f(pm.z); dA.w = exp2f(pm.w);
            const float dtu = dtv * uv;
            h  = dA * h + dtu * Bv;
            cp = cp * dA;
            const f32x4 cg = Cv * gv;
            acc = h * cg + acc;
            wc  = cp * cg + wc;
            ug  = fmaf(uv, gv, ug);
        }
        if (ck + 1 < kSEGL / kCT) {
            __syncthreads();
            store_chunk();
            __syncthreads();
        }
    }

    // coalesced: [seg][sq][b*kDI+d][4] — lane stride 16B
    const size_t o = (size_t)seg * kP + ((size_t)sq * kBD + b * kDI + d) * 4;
    *(f32x4*)&PA[o]   = cp;
    *(f32x4*)&QA[o]   = h;
    *(f32x4*)&accA[o] = acc;
    *(f32x4*)&wcA[o]  = wc;
    if (sq == 0) ugA[(size_t)seg * kBD + b * kDI + d] = ug;
}

// Pass 2: chain segments (transposed layout), reduce states, add D*ug.
__global__ __launch_bounds__(256) void scan_combine_kernel(
    const float* __restrict__ PA, const float* __restrict__ QA,
    const float* __restrict__ accA, const float* __restrict__ wcA,
    const float* __restrict__ ugA, const float* __restrict__ Dvec,
    float* __restrict__ ysum)
{
    const int p = blockIdx.x * 256 + threadIdx.x;   // 0..kP-1
    const int s = p & 15;
    const int bd = p >> 4;                          // b*kDI + d
    const size_t pbase = ((size_t)(s >> 2) * kBD + bd) * 4 + (s & 3);
    float h = 0.f, tot = 0.f;
    #pragma unroll
    for (int seg = 0; seg < kNSEG; ++seg) {
        const size_t o = (size_t)seg * kP + pbase;
        tot += accA[o] + h * wcA[o];
        h = fmaf(PA[o], h, QA[o]);
    }
    #pragma unroll
    for (int o2 = 1; o2 < 16; o2 <<= 1) tot += __shfl_xor(tot, o2, 64);
    if (s == 0) {
        float ug = 0.f;
        #pragma unroll
        for (int seg = 0; seg < kNSEG; ++seg)
            ug += ugA[(size_t)seg * kBD + bd];
        ysum[bd] = tot + Dvec[bd % kDI] * ug;
    }
}

// ---------------------------------------------------------------------------
// out[b][j] = (1/L) * sum_d ysum[b][d] * Wout[j][d]
__global__ __launch_bounds__(256) void final_kernel(
    const float* __restrict__ ysum, const float* __restrict__ Wout,
    float* __restrict__ out)
{
    int gw = blockIdx.x * 4 + (threadIdx.x >> 6);
    int lane = threadIdx.x & 63;
    int b = gw / kDM;
    int j = gw - b * kDM;
    const float* yrow = ysum + (size_t)b * kDI;
    const float* wrow = Wout + (size_t)j * kDI;
    float acc = 0.f;
    for (int k = lane; k < kDI; k += 64) acc = fmaf(yrow[k], wrow[k], acc);
    #pragma unroll
    for (int o = 32; o; o >>= 1) acc += __shfl_xor(acc, o, 64);
    if (lane == 0) out[gw] = acc * (1.f / (float)kL);
}

// ---------------------------------------------------------------------------
extern "C" void kernel_launch(void* const* d_in, const int* in_sizes, int n_in,
                              void* d_out, int out_size, void* d_ws, size_t ws_size,
                              hipStream_t stream)
{
    const float* image_tokens = (const float*)d_in[0];
    const float* text_tokens  = (const float*)d_in[1];
    const float* W_txt        = (const float*)d_in[2];
    const float* b_txt        = (const float*)d_in[3];
    const float* in_proj_w    = (const float*)d_in[4];
    const float* conv_w       = (const float*)d_in[5];
    const float* conv_b       = (const float*)d_in[6];
    const float* x_proj_w     = (const float*)d_in[7];
    const float* dt_proj_w    = (const float*)d_in[8];
    const float* dt_proj_b    = (const float*)d_in[9];
    const float* A_log        = (const float*)d_in[10];
    const float* Dvec         = (const float*)d_in[11];
    const float* out_proj_w   = (const float*)d_in[12];
    float* out = (float*)d_out;

    // workspace layout (bytes, all 256B-aligned). Region lifetimes:
    //   dtreg: tokb+wb (until in_proj) -> part (xproj) -> dt bf16 (dtproj..scan)
    //   xrawR: xraw bf16 (conv input) -> PA/QA/accA/wcA partials (scan..combine)
    char* p = (char*)d_ws;
    float* txt  = (float*)p;                      p += 12288;
    float* dtreg = (float*)p;                     p += (size_t)kM * kDI * 4;       // 25.2 MB
    float* xrawR = (float*)p;                     p += (size_t)kM * kDI * 4;       // 25.2 MB
    unsigned short* gbuf = (unsigned short*)p;    p += (size_t)kM * kDI * 2;       // 12.6 MB
    unsigned short* xbuf = (unsigned short*)p;    p += (size_t)kM * kDI * 2;       // 12.6 MB
    float* xdbl = (float*)p;                      p += (size_t)kM * kNX * 4;       // 1.3 MB
    float* ysum = (float*)p;                      p += 32768;
    float* ugA  = (float*)p;                      p += (size_t)kNSEG * kBD * 4;    // 0.4 MB

    unsigned short* tokb = (unsigned short*)dtreg;          // 6.3 MB
    unsigned short* wb   = tokb + (size_t)kM * kDM;         // 4.7 MB
    float* part = dtreg;                                    // 10.5 MB (after in_proj)
    unsigned short* dtb = (unsigned short*)dtreg;           // 12.6 MB (after xproj)
    unsigned short* xraw = (unsigned short*)xrawR;          // 12.6 MB bf16
    float* PA   = xrawR;                                    // partials (xraw dead after conv)
    float* QA   = PA + (size_t)kNSEG * kP;
    float* accA = QA + (size_t)kNSEG * kP;
    float* wcA  = accA + (size_t)kNSEG * kP;

    // 1) txt projection
    txt_kernel<<<dim3(kB * kDM / 4), dim3(256), 0, stream>>>(text_tokens, W_txt, b_txt, txt);

    // 2) merged prep: tokens = bf16(image + txt)  +  cast in_proj_w -> bf16
    prep_kernel<<<dim3(3072 + 2304), dim3(256), 0, stream>>>(
        image_tokens, txt, tokb, in_proj_w, wb);

    // 3) in_proj (bf16 MFMA): x half -> xraw (bf16), z half -> g = bf16(silu(z))
    mfma_inproj_kernel<<<dim3(kM / 128, 2 * kDI / 128), dim3(256), 0, stream>>>(
        tokb, wb, xraw, gbuf);

    // 4) causal conv + silu (bf16 in/out, 8 channels/thread)
    conv_silu_kernel<<<dim3(kM * kDI / 8 / 256), dim3(256), 0, stream>>>(
        xraw, conv_w, conv_b, xbuf);

    // 5) x_proj split-K (bf16 A; part overlays dtreg; tokb/wb dead now)
    xproj_splitk_kernel<<<dim3(kM / 64, kKS), dim3(256), 0, stream>>>(xbuf, x_proj_w, part);
    xproj_reduce_kernel<<<dim3(kM * kNX / 256), dim3(256), 0, stream>>>(part, xdbl);

    // 6) dt_proj -> bf16 dtb (overlays dtreg; part dead now)
    dtproj_gemm_kernel<<<dim3(kM / 64, kDI / 64), dim3(256), 0, stream>>>(
        xdbl, dt_proj_w, dt_proj_b, dtb);

    // 7) full-residency segmented scan (bf16 u/g/dt) + combine
    scan12_kernel<<<dim3(kB * 24 * kNSEG), dim3(256), 0, stream>>>(
        xbuf, gbuf, dtb, xdbl, A_log, PA, QA, accA, wcA, ugA);
    scan_combine_kernel<<<dim3(kP / 256), dim3(256), 0, stream>>>(
        PA, QA, accA, wcA, ugA, Dvec, ysum);

    // 8) out = (ysum/L) @ out_proj_w.T
    final_kernel<<<dim3(kB * kDM / 4), dim3(256), 0, stream>>>(ysum, out_proj_w, out);
}